// Round 1
// baseline (216.341 us; speedup 1.0000x reference)
//
#include <hip/hip_runtime.h>
#include <stdint.h>

#define KSTEPS 24              // 768 / 32
#define TOKENS 16384           // B*S

typedef short short8 __attribute__((ext_vector_type(8)));
typedef float fx4 __attribute__((ext_vector_type(4)));
typedef unsigned short u16;
typedef u16 u16x4 __attribute__((ext_vector_type(4)));

static __device__ __forceinline__ u16 f2bf(float f) {
  union { float f; unsigned u; } v; v.f = f;
  return (u16)((v.u + 0x7fffu + ((v.u >> 16) & 1u)) >> 16);
}

static __device__ __forceinline__ fx4 mfma16(short8 a, short8 b, fx4 c) {
  return __builtin_amdgcn_mfma_f32_16x16x32_bf16(a, b, c, 0, 0, 0);
}

// async global->LDS, 16B per lane; lds dest = wave-uniform base + lane*16
static __device__ __forceinline__ void async16(const void* g, void* l) {
  __builtin_amdgcn_global_load_lds(
      (const __attribute__((address_space(1))) void*)g,
      (__attribute__((address_space(3))) void*)(unsigned int)(uintptr_t)l,
      16, 0, 0);
}

// ---------------- prep: W[768][64] fp32 (q,k,v) -> bf16 pre-fragmented B-operand layout
// wfrag[mat][ks][nt][lane][8]; elem j = W[ks*32 + (lane>>4)*8 + j][nt*16 + (lane&15)]
__global__ void prep_w_kernel(const float* __restrict__ Wq, const float* __restrict__ Wk,
                              const float* __restrict__ Wv, u16* __restrict__ wfrag) {
  int idx  = blockIdx.x * 256 + threadIdx.x;   // 72*256 = 18432 = 3*24*4*64 exactly
  int lane = idx & 63;
  int fid  = idx >> 6;                          // 0..287
  int nt   = fid & 3;
  int ks   = (fid >> 2) % KSTEPS;
  int mat  = fid / (KSTEPS * 4);
  const float* W = (mat == 0) ? Wq : (mat == 1) ? Wk : Wv;
  int n  = nt * 16 + (lane & 15);
  int k0 = ks * 32 + (lane >> 4) * 8;
  short8 out;
#pragma unroll
  for (int j = 0; j < 8; j++) out[j] = (short)f2bf(W[(size_t)(k0 + j) * 64 + n]);
  *(short8*)(wfrag + (size_t)idx * 8) = out;
}

// ---------------- projection: q = 0.125*(x Wq) bf16, k = x Wk bf16, vT = (x Wv)^T bf16
// No LDS: A-frags direct from global x (fp32->bf16), B-frags direct from wfrag.
__global__ __launch_bounds__(256) void proj_kernel(const float* __restrict__ x,
                                                   const u16* __restrict__ wfrag,
                                                   u16* __restrict__ qb,
                                                   u16* __restrict__ kb,
                                                   u16* __restrict__ vT) {
  int w = threadIdx.x >> 6, lane = threadIdx.x & 63;
  int ln = lane & 15, quad = lane >> 4;
  int s0 = blockIdx.x * 64;
  int arow = s0 + w * 16 + ln;                  // A-operand row (token)

  fx4 acc[3][4];
#pragma unroll
  for (int m = 0; m < 3; m++)
#pragma unroll
    for (int nt = 0; nt < 4; nt++) acc[m][nt] = (fx4){0.f, 0.f, 0.f, 0.f};

  const float* xp = x + (size_t)arow * 768 + quad * 8;
  for (int ks = 0; ks < KSTEPS; ks++) {
    fx4 xa = *(const fx4*)(xp + ks * 32);
    fx4 xb = *(const fx4*)(xp + ks * 32 + 4);
    short8 af;
#pragma unroll
    for (int j = 0; j < 4; j++) { af[j] = (short)f2bf(xa[j]); af[4 + j] = (short)f2bf(xb[j]); }
    const u16* wp = wfrag + ((size_t)ks * 256 + lane) * 8;
#pragma unroll
    for (int m = 0; m < 3; m++) {
#pragma unroll
      for (int nt = 0; nt < 4; nt++) {
        short8 bf = *(const short8*)(wp + ((size_t)m * KSTEPS * 256 + nt * 64) * 8);
        acc[m][nt] = mfma16(af, bf, acc[m][nt]);
      }
    }
  }
  // epilogue: C/D layout col = lane&15, row = quad*4 + reg
#pragma unroll
  for (int nt = 0; nt < 4; nt++) {
    int d = nt * 16 + ln;
    int tok0 = s0 + w * 16 + quad * 4;
#pragma unroll
    for (int reg = 0; reg < 4; reg++) {
      int tok = tok0 + reg;
      qb[(size_t)tok * 64 + d] = f2bf(acc[0][nt][reg] * 0.125f);  // pre-scale by 1/sqrt(64)
      kb[(size_t)tok * 64 + d] = f2bf(acc[1][nt][reg]);
    }
    int b = tok0 >> 12, s = tok0 & 4095;
    u16x4 vp;
#pragma unroll
    for (int reg = 0; reg < 4; reg++) vp[reg] = f2bf(acc[2][nt][reg]);
    *(u16x4*)(vT + ((size_t)b * 64 + d) * 4096 + s) = vp;          // V^T scatter, 8B chunks
  }
}

// ---------------- flash attention, causal, BM=BN=64, D=64, 4 waves (16 Q-rows each)
__global__ __launch_bounds__(256) void attn_kernel(const u16* __restrict__ qb,
                                                   const u16* __restrict__ kb,
                                                   const u16* __restrict__ vT,
                                                   float* __restrict__ out) {
  __shared__ u16 Ks[64 * 64];        // [key][d]   8 KB (global_load_lds: no pad)
  __shared__ u16 VTs[64 * 64];       // [d][key]   8 KB
  __shared__ u16 Ps[4][16 * 72];     // per-wave P, rows padded to 72 bf16

  int qt = blockIdx.x, b = blockIdx.y;
  int w = threadIdx.x >> 6, lane = threadIdx.x & 63;
  int ln = lane & 15, quad = lane >> 4;
  int q0 = qt * 64;

  const u16* qbb = qb + (size_t)b * 4096 * 64;
  const u16* kbb = kb + (size_t)b * 4096 * 64;
  const u16* vtb = vT + (size_t)b * 64 * 4096;
  float* outb = out + (size_t)b * 4096 * 64;

  // Q A-frags resident in registers for the whole kernel
  short8 qf0 = *(const short8*)(qbb + (size_t)(q0 + w * 16 + ln) * 64 + quad * 8);
  short8 qf1 = *(const short8*)(qbb + (size_t)(q0 + w * 16 + ln) * 64 + 32 + quad * 8);

  fx4 o[4];
#pragma unroll
  for (int nt2 = 0; nt2 < 4; nt2++) o[nt2] = (fx4){0.f, 0.f, 0.f, 0.f};
  float m_i[4] = {-1e30f, -1e30f, -1e30f, -1e30f};
  float l_i[4] = {0.f, 0.f, 0.f, 0.f};

  for (int kt = 0; kt <= qt; kt++) {
    __syncthreads();   // previous iteration's LDS reads done before restage
#pragma unroll
    for (int j = 0; j < 2; j++) {
      int loff = (w * 2 + j) * 1024;            // bytes, wave-uniform LDS base
      int flat = loff + lane * 16;              // byte offset inside the 8 KB tile
      // K tile [key][d] is contiguous in global
      async16(kbb + (size_t)kt * 4096 + (flat >> 1), (char*)Ks + loff);
      // V^T tile [d][key]: row d of global vT, 16B chunk of keys
      int d = flat >> 7, kk = (flat & 127) >> 1;
      async16(vtb + (size_t)d * 4096 + kt * 64 + kk, (char*)VTs + loff);
    }
    __syncthreads();   // drains vmcnt: staging visible to all waves

    // S = Q K^T (pre-scaled): 2 k-steps x 4 n-tiles
    fx4 sA[4];
#pragma unroll
    for (int nt = 0; nt < 4; nt++) {
      sA[nt] = (fx4){0.f, 0.f, 0.f, 0.f};
      short8 kf0 = *(const short8*)(Ks + (nt * 16 + ln) * 64 + quad * 8);
      short8 kf1 = *(const short8*)(Ks + (nt * 16 + ln) * 64 + 32 + quad * 8);
      sA[nt] = mfma16(qf0, kf0, sA[nt]);
      sA[nt] = mfma16(qf1, kf1, sA[nt]);
    }

    if (kt == qt) {  // only the diagonal tile needs masking
#pragma unroll
      for (int nt = 0; nt < 4; nt++)
#pragma unroll
        for (int reg = 0; reg < 4; reg++) {
          int col = nt * 16 + ln, row = w * 16 + quad * 4 + reg;
          if (col > row) sA[nt][reg] = -1e30f;
        }
    }

    // online softmax; row = quad*4+reg, all 16 lanes of a quad share rows
    float alpha[4];
#pragma unroll
    for (int reg = 0; reg < 4; reg++) {
      float v = fmaxf(fmaxf(sA[0][reg], sA[1][reg]), fmaxf(sA[2][reg], sA[3][reg]));
#pragma unroll
      for (int off = 1; off < 16; off <<= 1) v = fmaxf(v, __shfl_xor(v, off));
      float mn = fmaxf(m_i[reg], v);
      alpha[reg] = __expf(m_i[reg] - mn);
      m_i[reg] = mn;
    }
    float p[4][4];
#pragma unroll
    for (int nt = 0; nt < 4; nt++)
#pragma unroll
      for (int reg = 0; reg < 4; reg++) p[nt][reg] = __expf(sA[nt][reg] - m_i[reg]);
#pragma unroll
    for (int reg = 0; reg < 4; reg++) {
      float sgm = p[0][reg] + p[1][reg] + p[2][reg] + p[3][reg];
#pragma unroll
      for (int off = 1; off < 16; off <<= 1) sgm += __shfl_xor(sgm, off);
      l_i[reg] = l_i[reg] * alpha[reg] + sgm;
    }
#pragma unroll
    for (int nt2 = 0; nt2 < 4; nt2++)
#pragma unroll
      for (int reg = 0; reg < 4; reg++) o[nt2][reg] *= alpha[reg];

    // P: C-layout -> A-layout via wave-private LDS round-trip (m120 pattern)
#pragma unroll
    for (int nt = 0; nt < 4; nt++)
#pragma unroll
      for (int reg = 0; reg < 4; reg++)
        Ps[w][(quad * 4 + reg) * 72 + nt * 16 + ln] = f2bf(p[nt][reg]);

    short8 pf0 = *(const short8*)(&Ps[w][ln * 72 + quad * 8]);
    short8 pf1 = *(const short8*)(&Ps[w][ln * 72 + 32 + quad * 8]);
#pragma unroll
    for (int nt2 = 0; nt2 < 4; nt2++) {
      short8 vf0 = *(const short8*)(VTs + (nt2 * 16 + ln) * 64 + quad * 8);
      short8 vf1 = *(const short8*)(VTs + (nt2 * 16 + ln) * 64 + 32 + quad * 8);
      o[nt2] = mfma16(pf0, vf0, o[nt2]);
      o[nt2] = mfma16(pf1, vf1, o[nt2]);
    }
  }

  float inv[4];
#pragma unroll
  for (int reg = 0; reg < 4; reg++) inv[reg] = 1.0f / l_i[reg];
#pragma unroll
  for (int nt2 = 0; nt2 < 4; nt2++)
#pragma unroll
    for (int reg = 0; reg < 4; reg++)
      outb[(size_t)(q0 + w * 16 + quad * 4 + reg) * 64 + nt2 * 16 + ln] =
          o[nt2][reg] * inv[reg];
}

extern "C" void kernel_launch(void* const* d_in, const int* in_sizes, int n_in,
                              void* d_out, int out_size, void* d_ws, size_t ws_size,
                              hipStream_t stream) {
  const float* x  = (const float*)d_in[0];
  const float* Wq = (const float*)d_in[1];
  const float* Wk = (const float*)d_in[2];
  const float* Wv = (const float*)d_in[3];

  u16* qbw = (u16*)d_ws;                          // [16384][64] bf16, 2 MB
  u16* kbw = qbw + (size_t)TOKENS * 64;           // [16384][64] bf16, 2 MB
  u16* vtw = kbw + (size_t)TOKENS * 64;           // [4][64][4096] bf16, 2 MB
  u16* wfr = vtw + (size_t)TOKENS * 64;           // [3][24][4][64][8] bf16, 288 KB

  prep_w_kernel<<<72, 256, 0, stream>>>(Wq, Wk, Wv, wfr);
  proj_kernel<<<TOKENS / 64, 256, 0, stream>>>(x, wfr, qbw, kbw, vtw);
  attn_kernel<<<dim3(64, 4), 256, 0, stream>>>(qbw, kbw, vtw, (float*)d_out);
}